// Round 14
// baseline (181.846 us; speedup 1.0000x reference)
//
#include <hip/hip_runtime.h>
#include <hip/hip_bf16.h>
#include <math.h>

// WeightsOnlyAttention: qk proj (bf16 MFMA) -> causal softmax over k ->
// LayerNorm across S=16 heads -> out (4,16,1024,1024) fp32.
// B=4 P=1024 E=768 S=16 H=64.

typedef __bf16 bf16_t;
typedef __bf16 bf16x4_t __attribute__((ext_vector_type(4)));
typedef __bf16 bf16x8_t __attribute__((ext_vector_type(8)));
typedef float  f32x4_t  __attribute__((ext_vector_type(4)));
typedef float  f32x16_t __attribute__((ext_vector_type(16)));

#define DEV __device__ __forceinline__
static constexpr float kLog2e = 1.4426950408889634f;

DEV void gload_lds16(const bf16_t* g, bf16_t* l) {
  __builtin_amdgcn_global_load_lds(
      (const __attribute__((address_space(1))) void*)g,
      (__attribute__((address_space(3))) void*)l, 16, 0, 0);
}

// ---------------- x (f32) -> xb (bf16), 4096x768 ----------------
__global__ __launch_bounds__(256) void k_cvt_x(const float* __restrict__ x,
                                               bf16_t* __restrict__ xb) {
  size_t i = ((size_t)blockIdx.x * 256 + threadIdx.x) * 8;
  f32x4_t a = *(const f32x4_t*)(x + i);
  f32x4_t b = *(const f32x4_t*)(x + i + 4);
  bf16x8_t o = {(bf16_t)a[0], (bf16_t)a[1], (bf16_t)a[2], (bf16_t)a[3],
                (bf16_t)b[0], (bf16_t)b[1], (bf16_t)b[2], (bf16_t)b[3]};
  *(bf16x8_t*)(xb + i) = o;
}

// ------------- W [768][2048] f32 -> Wt [2048][768] bf16 -------------
__global__ __launch_bounds__(256) void k_tr_w(const float* __restrict__ W,
                                              bf16_t* __restrict__ Wt) {
  __shared__ float t[32][33];
  int n0 = blockIdx.x * 32, e0 = blockIdx.y * 32;
  int tx = threadIdx.x & 31, ty = threadIdx.x >> 5;  // 32x8
#pragma unroll
  for (int i = 0; i < 4; i++)
    t[ty + 8 * i][tx] = W[(size_t)(e0 + ty + 8 * i) * 2048 + n0 + tx];
  __syncthreads();
#pragma unroll
  for (int i = 0; i < 4; i++)
    Wt[(size_t)(n0 + ty + 8 * i) * 768 + e0 + tx] = (bf16_t)t[tx][ty + 8 * i];
}

// ---------------- projection GEMM: C = xb * Wt^T + bias ----------------
// M=4096 (b,p), N=2048 (qk,s,h), K=768. 128x128 tile, BK=32, 4 waves.
// 1D grid 512, bijective XCD swizzle (neutral-to-slightly-positive, kept).
// Epilogue: q = (C+b)*0.125 -> q_ws[b][s][p][h] bf16 ; k -> k_ws.
__global__ __launch_bounds__(256) void k_proj(const bf16_t* __restrict__ xb,
                                              const bf16_t* __restrict__ Wt,
                                              const float* __restrict__ bias,
                                              bf16_t* __restrict__ q_ws,
                                              bf16_t* __restrict__ k_ws) {
  __shared__ bf16_t As[128 * 32];
  __shared__ bf16_t Bs[128 * 32];
  const int tid = threadIdx.x;
  const int lane = tid & 63;
  const int w = tid >> 6;
  const int raw = blockIdx.x;                  // 0..511
  const int swz = (raw & 7) * 64 + (raw >> 3); // XCD-contiguous chunks of 64
  const int m0 = (swz >> 4) * 128;             // 32 m-tiles
  const int n0 = (swz & 15) * 128;             // 16 n-tiles
  const int mw = (w >> 1) * 64, nw = (w & 1) * 64;

  f32x4_t zz = {0.f, 0.f, 0.f, 0.f};
  f32x4_t acc[4][4];
#pragma unroll
  for (int mt = 0; mt < 4; mt++)
#pragma unroll
    for (int nt = 0; nt < 4; nt++) acc[mt][nt] = zz;

  for (int k0 = 0; k0 < 768; k0 += 32) {
    __syncthreads();
#pragma unroll
    for (int i = 0; i < 2; i++) {
      int cbase = w * 128 + i * 64;     // 16B-chunk base for this wave-instr
      int c = cbase + lane;             // chunk: row = c>>2, 8-elem quarter = c&3
      int r = c >> 2, q8 = c & 3;
      gload_lds16(xb + (size_t)(m0 + r) * 768 + k0 + q8 * 8, As + cbase * 8);
      gload_lds16(Wt + (size_t)(n0 + r) * 768 + k0 + q8 * 8, Bs + cbase * 8);
    }
    __syncthreads();
    bf16x8_t a[4], b[4];
#pragma unroll
    for (int mt = 0; mt < 4; mt++)
      a[mt] = *(const bf16x8_t*)(As + (mw + mt * 16 + (lane & 15)) * 32 + (lane >> 4) * 8);
#pragma unroll
    for (int nt = 0; nt < 4; nt++)
      b[nt] = *(const bf16x8_t*)(Bs + (nw + nt * 16 + (lane & 15)) * 32 + (lane >> 4) * 8);
#pragma unroll
    for (int mt = 0; mt < 4; mt++)
#pragma unroll
      for (int nt = 0; nt < 4; nt++)
        acc[mt][nt] = __builtin_amdgcn_mfma_f32_16x16x32_bf16(a[mt], b[nt], acc[mt][nt], 0, 0, 0);
  }

#pragma unroll
  for (int mt = 0; mt < 4; mt++) {
    int row0 = mw + mt * 16 + (lane >> 4) * 4;
#pragma unroll
    for (int nt = 0; nt < 4; nt++) {
      int col = nw + nt * 16 + (lane & 15);
      int n = n0 + col;
      int s = (n >> 6) & 15, h = n & 63, qk = n >> 10;
      float bv = bias[n];
#pragma unroll
      for (int j = 0; j < 4; j++) {
        int m = m0 + row0 + j;
        int bi = m >> 10, p = m & 1023;
        float v = acc[mt][nt][j] + bv;
        size_t off = ((size_t)(bi * 16 + s) * 1024 + p) * 64 + h;
        if (qk == 0) q_ws[off] = (bf16_t)(v * 0.125f);
        else         k_ws[off] = (bf16_t)v;
      }
    }
  }
}

// ---------------- rl[b][s][p] = 1 / sum_{k<=p} exp(score) ----------------
// grid (8 pblocks, 64 bs), 4 waves x 32 rows each via SWAPPED 32x32x16 MFMA
// (A=K rows=k, B=Q rows=p): C col = p (one p per lane), 16 regs = k-values.
// Row-sum is lane-local over regs/kt + one shfl_xor(32) for the hi half.
__global__ __launch_bounds__(256) void k_sumexp(const bf16_t* __restrict__ q_ws,
                                                const bf16_t* __restrict__ k_ws,
                                                float* __restrict__ rl_ws) {
  const int tid = threadIdx.x, lane = tid & 63, w = tid >> 6;
  const int bs = blockIdx.y;
  const int r0 = blockIdx.x * 128 + w * 32;
  const size_t base = (size_t)bs * 65536;  // 1024*64
  const int col = lane & 31, hi = lane >> 5;
  const int p = r0 + col;

  bf16x8_t qb[4];
  const bf16_t* qrow = q_ws + base + (size_t)p * 64 + hi * 8;
#pragma unroll
  for (int t = 0; t < 4; t++) qb[t] = *(const bf16x8_t*)(qrow + t * 16);

  float sum = 0.f;
  const int ktmax = r0 >> 5;
  for (int kt = 0; kt <= ktmax; kt++) {
    const bf16_t* krow = k_ws + base + (size_t)(kt * 32 + col) * 64 + hi * 8;
    bf16x8_t ka[4];
#pragma unroll
    for (int t = 0; t < 4; t++) ka[t] = *(const bf16x8_t*)(krow + t * 16);
    f32x16_t c;
#pragma unroll
    for (int j = 0; j < 16; j++) c[j] = 0.f;
#pragma unroll
    for (int t = 0; t < 4; t++)
      c = __builtin_amdgcn_mfma_f32_32x32x16_bf16(ka[t], qb[t], c, 0, 0, 0);
#pragma unroll
    for (int j = 0; j < 16; j++) {
      int kk = kt * 32 + (j & 3) + 8 * (j >> 2) + 4 * hi;
      if (kk <= p) sum += exp2f(c[j] * kLog2e);
    }
  }
  sum += __shfl_xor(sum, 32, 64);
  if (hi == 0) rl_ws[(size_t)bs * 1024 + p] = 1.0f / sum;
}

// ---- k_final tile body: exact R8 compute/reduce/store for one 32x32 tile ----
// FIRST=true inserts the rl_lds-ready barrier after the MFMAs (call 1 only).
// Straight-line when inlined twice with distinct part buffers; no runtime
// loop (R12's loop spilled the accumulators -- rule #20).
template <bool FIRST>
DEV void tile_body(const bf16_t* __restrict__ q_ws,
                   const bf16_t* __restrict__ k_ws,
                   const float* __restrict__ ln_scale,
                   const float* __restrict__ ln_bias,
                   float* __restrict__ out,
                   float2 (*__restrict__ part)[1024],
                   const float* __restrict__ rl_lds,
                   int bb, int pbase, int kbase, int w, int lane) {
  const int col = lane & 31, hi = lane >> 5;
  const int kcol = kbase + col;
  const int s0 = w * 2, s1 = w * 2 + 1;

  // score tiles for this wave's 2 heads: A=Q (rows=p), B=K (rows=k)
  f32x16_t c0, c1;
#pragma unroll
  for (int j = 0; j < 16; j++) { c0[j] = 0.f; c1[j] = 0.f; }
  {
    size_t base0 = (size_t)(bb * 16 + s0) * 65536;
    const bf16_t* qrow = q_ws + base0 + (size_t)(pbase + col) * 64 + hi * 8;
    const bf16_t* krow = k_ws + base0 + (size_t)kcol * 64 + hi * 8;
#pragma unroll
    for (int t = 0; t < 4; t++)
      c0 = __builtin_amdgcn_mfma_f32_32x32x16_bf16(
          *(const bf16x8_t*)(qrow + t * 16), *(const bf16x8_t*)(krow + t * 16), c0, 0, 0, 0);
    qrow += 65536; krow += 65536;  // next head, same (b)
#pragma unroll
    for (int t = 0; t < 4; t++)
      c1 = __builtin_amdgcn_mfma_f32_32x32x16_bf16(
          *(const bf16x8_t*)(qrow + t * 16), *(const bf16x8_t*)(krow + t * 16), c1, 0, 0, 0);
  }

  if (FIRST) __syncthreads();  // rl_lds ready (placed after MFMA to overlap)

  // w = exp(score)*rl (causal), in place
#pragma unroll
  for (int j = 0; j < 16; j++) {
    int prl = (j & 3) + 8 * (j >> 2) + 4 * hi;
    bool ok = (kcol <= pbase + prl);
    float w0 = ok ? exp2f(c0[j] * kLog2e) * rl_lds[s0 * 32 + prl] : 0.f;
    float w1 = ok ? exp2f(c1[j] * kLog2e) * rl_lds[s1 * 32 + prl] : 0.f;
    c0[j] = w0; c1[j] = w1;
  }

  // stage-1: waves 0-3 write their 2-head partials
  if (w < 4) {
#pragma unroll
    for (int j = 0; j < 16; j++) {
      int prl = (j & 3) + 8 * (j >> 2) + 4 * hi;
      part[w][prl * 32 + col] =
          make_float2(c0[j] + c1[j], c0[j] * c0[j] + c1[j] * c1[j]);
    }
  }
  __syncthreads();
  // waves 4-7 accumulate into partner slot
  if (w >= 4) {
#pragma unroll
    for (int j = 0; j < 16; j++) {
      int prl = (j & 3) + 8 * (j >> 2) + 4 * hi;
      int cell = prl * 32 + col;
      float2 v = part[w - 4][cell];
      v.x += c0[j] + c1[j];
      v.y += c0[j] * c0[j] + c1[j] * c1[j];
      part[w - 4][cell] = v;
    }
  }
  __syncthreads();

  // stage-2: 512 threads x 2 cells; {mu,rstd} overwrites part[0]
  const int tid = w * 64 + lane;
#pragma unroll
  for (int r = 0; r < 2; r++) {
    int cell = tid + r * 512;
    float2 a = part[0][cell], b2 = part[1][cell];
    float2 cc = part[2][cell], d = part[3][cell];
    float sm = a.x + b2.x + cc.x + d.x;
    float sq = a.y + b2.y + cc.y + d.y;
    float m = sm * 0.0625f;
    part[0][cell] = make_float2(m, rsqrtf(sq * 0.0625f - m * m + 1e-5f));
  }
  __syncthreads();

  // stores: scalar dwords, nontemporal; lanes 0-31 cover one full 128B line
  // of row prl, lanes 32-63 the line of row prl+4. NO trailing barrier:
  // the next tile's MFMA issues while these drain.
  {
    float scl0 = ln_scale[s0], bi0 = ln_bias[s0];
    float scl1 = ln_scale[s1], bi1 = ln_bias[s1];
    size_t hb0 = ((size_t)(bb * 16 + s0) * 1024 + pbase) * 1024 + kbase;
    size_t hb1 = hb0 + (size_t)1048576;  // next head
#pragma unroll
    for (int j = 0; j < 16; j++) {
      int prl = (j & 3) + 8 * (j >> 2) + 4 * hi;
      float2 mr = part[0][prl * 32 + col];
      __builtin_nontemporal_store((c0[j] - mr.x) * mr.y * scl0 + bi0,
                                  &out[hb0 + (size_t)prl * 1024 + col]);
      __builtin_nontemporal_store((c1[j] - mr.x) * mr.y * scl1 + bi1,
                                  &out[hb1 + (size_t)prl * 1024 + col]);
    }
  }
}

// ------- final: recompute scores, w=exp*rl, LN over 16 heads, write -------
// R8 dataflow; TWO straight-line 32x32 k-tiles per block with DISTINCT LDS
// buffers (partA/partB) -> tile0's nt-store drain overlaps tile1's MFMA+exp
// (the phase-serialization fix R12 attempted; R12's runtime loop spilled --
// this version is two inlined calls, no loop-carried vector state).
// Masked fills issued first so they drain under compute. Grid 2048.
__global__ __launch_bounds__(512, 4) void k_final(const bf16_t* __restrict__ q_ws,
                                                  const bf16_t* __restrict__ k_ws,
                                                  const float* __restrict__ rl_ws,
                                                  const float* __restrict__ ln_scale,
                                                  const float* __restrict__ ln_bias,
                                                  float* __restrict__ out) {
  const int tid = threadIdx.x, lane = tid & 63, w = tid >> 6;  // w in [0,8)
  const int raw = blockIdx.x;
  const int swz = (raw & 7) * 256 + (raw >> 3);  // XCD-contiguous, 2048 blocks
  const int bb = swz >> 9, pb = (swz >> 4) & 31, kbp = swz & 15;
  const int pbase = pb * 32;
  const int kbase0 = kbp * 64, kbase1 = kbase0 + 32;

  const bool act0 = kbase0 <= pbase + 31;
  const bool act1 = kbase1 <= pbase + 31;

  // ---- masked fills first: nt stores drain under later compute ----
  if (!act0) {
#pragma unroll
    for (int it = 0; it < 8; it++) {
      int idx = it * 512 + tid;
      int s = idx >> 8, rem = idx & 255;
      int pl = rem >> 3, kq = (rem & 7) * 4;
      float bv = ln_bias[s];
      f32x4_t v = {bv, bv, bv, bv};
      __builtin_nontemporal_store(
          v, (f32x4_t*)(out + ((size_t)(bb * 16 + s) * 1024 + pbase + pl) * 1024 + kbase0 + kq));
    }
  }
  if (!act1) {
#pragma unroll
    for (int it = 0; it < 8; it++) {
      int idx = it * 512 + tid;
      int s = idx >> 8, rem = idx & 255;
      int pl = rem >> 3, kq = (rem & 7) * 4;
      float bv = ln_bias[s];
      f32x4_t v = {bv, bv, bv, bv};
      __builtin_nontemporal_store(
          v, (f32x4_t*)(out + ((size_t)(bb * 16 + s) * 1024 + pbase + pl) * 1024 + kbase1 + kq));
    }
  }
  if (!act0) return;  // kbase1 > kbase0 => both masked

  __shared__ float2 partA[4][1024];  // tile0 reduce buffer (32KB)
  __shared__ float2 partB[4][1024];  // tile1 reduce buffer (32KB)
  __shared__ float  rl_lds[512];     // [s*32 + pr]

  // stage rl once: shared by both tiles (same pbase)
  rl_lds[tid] = rl_ws[(size_t)(bb * 16 + (tid >> 5)) * 1024 + pbase + (tid & 31)];

  tile_body<true>(q_ws, k_ws, ln_scale, ln_bias, out, partA, rl_lds,
                  bb, pbase, kbase0, w, lane);
  if (act1)
    tile_body<false>(q_ws, k_ws, ln_scale, ln_bias, out, partB, rl_lds,
                     bb, pbase, kbase1, w, lane);
}

extern "C" void kernel_launch(void* const* d_in, const int* in_sizes, int n_in,
                              void* d_out, int out_size, void* d_ws, size_t ws_size,
                              hipStream_t stream) {
  (void)in_sizes; (void)n_in; (void)out_size; (void)ws_size;
  const float* x        = (const float*)d_in[0];
  // d_in[1] = mask (causal tril; structure hardcoded)
  const float* W        = (const float*)d_in[2];
  const float* bias     = (const float*)d_in[3];
  const float* ln_scale = (const float*)d_in[4];
  const float* ln_bias  = (const float*)d_in[5];
  float* out = (float*)d_out;

  char* ws = (char*)d_ws;
  bf16_t* q_ws = (bf16_t*)ws;                    //  8,388,608 B [b][s][p][h]
  bf16_t* k_ws = (bf16_t*)(ws + 8388608);        //  8,388,608 B
  float*  rl_ws = (float*)(ws + 16777216);       //    262,144 B [b][s][p]
  bf16_t* xb   = (bf16_t*)(ws + 17039360);       //  6,291,456 B [4096][768]
  bf16_t* Wt   = (bf16_t*)(ws + 23330816);       //  3,145,728 B [2048][768]

  k_cvt_x<<<dim3(1536), 256, 0, stream>>>(x, xb);
  k_tr_w <<<dim3(64, 24), 256, 0, stream>>>(W, Wt);
  k_proj <<<dim3(512), 256, 0, stream>>>(xb, Wt, bias, q_ws, k_ws);
  k_sumexp<<<dim3(8, 64), 256, 0, stream>>>(q_ws, k_ws, rl_ws);
  k_final<<<dim3(2048), 512, 0, stream>>>(q_ws, k_ws, rl_ws, ln_scale, ln_bias, out);
}

// Round 15
// 173.072 us; speedup vs baseline: 1.0507x; 1.0507x over previous
//
#include <hip/hip_runtime.h>
#include <hip/hip_bf16.h>
#include <math.h>

// WeightsOnlyAttention: qk proj (bf16 MFMA) -> causal softmax over k ->
// LayerNorm across S=16 heads -> out (4,16,1024,1024) fp32.
// B=4 P=1024 E=768 S=16 H=64.

typedef __bf16 bf16_t;
typedef __bf16 bf16x4_t __attribute__((ext_vector_type(4)));
typedef __bf16 bf16x8_t __attribute__((ext_vector_type(8)));
typedef float  f32x4_t  __attribute__((ext_vector_type(4)));
typedef float  f32x16_t __attribute__((ext_vector_type(16)));

#define DEV __device__ __forceinline__
static constexpr float kLog2e = 1.4426950408889634f;

DEV void gload_lds16(const bf16_t* g, bf16_t* l) {
  __builtin_amdgcn_global_load_lds(
      (const __attribute__((address_space(1))) void*)g,
      (__attribute__((address_space(3))) void*)l, 16, 0, 0);
}

// ---- fused prep: x->bf16 (blocks 0..1535) | W transpose (1536..3071) ----
__global__ __launch_bounds__(256) void k_prep(const float* __restrict__ x,
                                              bf16_t* __restrict__ xb,
                                              const float* __restrict__ W,
                                              bf16_t* __restrict__ Wt) {
  if (blockIdx.x < 1536) {
    size_t i = ((size_t)blockIdx.x * 256 + threadIdx.x) * 8;
    f32x4_t a = *(const f32x4_t*)(x + i);
    f32x4_t b = *(const f32x4_t*)(x + i + 4);
    bf16x8_t o = {(bf16_t)a[0], (bf16_t)a[1], (bf16_t)a[2], (bf16_t)a[3],
                  (bf16_t)b[0], (bf16_t)b[1], (bf16_t)b[2], (bf16_t)b[3]};
    *(bf16x8_t*)(xb + i) = o;
  } else {
    __shared__ float t[32][33];
    int b = blockIdx.x - 1536;           // 0..1535 = 64 n-blocks x 24 e-blocks
    int n0 = (b & 63) * 32, e0 = (b >> 6) * 32;
    int tx = threadIdx.x & 31, ty = threadIdx.x >> 5;  // 32x8
#pragma unroll
    for (int i = 0; i < 4; i++)
      t[ty + 8 * i][tx] = W[(size_t)(e0 + ty + 8 * i) * 2048 + n0 + tx];
    __syncthreads();
#pragma unroll
    for (int i = 0; i < 4; i++)
      Wt[(size_t)(n0 + ty + 8 * i) * 768 + e0 + tx] = (bf16_t)t[tx][ty + 8 * i];
  }
}

// ---------------- projection GEMM: C = xb * Wt^T + bias ----------------
// M=4096 (b,p), N=2048 (qk,s,h), K=768. 128x128 tile, BK=32, 4 waves.
// 1D grid 512, bijective XCD swizzle.
// Epilogue: q = (C+b)*0.125 -> q_ws[b][s][p][h] bf16 ; k -> k_ws.
__global__ __launch_bounds__(256) void k_proj(const bf16_t* __restrict__ xb,
                                              const bf16_t* __restrict__ Wt,
                                              const float* __restrict__ bias,
                                              bf16_t* __restrict__ q_ws,
                                              bf16_t* __restrict__ k_ws) {
  __shared__ bf16_t As[128 * 32];
  __shared__ bf16_t Bs[128 * 32];
  const int tid = threadIdx.x;
  const int lane = tid & 63;
  const int w = tid >> 6;
  const int raw = blockIdx.x;                  // 0..511
  const int swz = (raw & 7) * 64 + (raw >> 3); // XCD-contiguous chunks of 64
  const int m0 = (swz >> 4) * 128;             // 32 m-tiles
  const int n0 = (swz & 15) * 128;             // 16 n-tiles
  const int mw = (w >> 1) * 64, nw = (w & 1) * 64;

  f32x4_t zz = {0.f, 0.f, 0.f, 0.f};
  f32x4_t acc[4][4];
#pragma unroll
  for (int mt = 0; mt < 4; mt++)
#pragma unroll
    for (int nt = 0; nt < 4; nt++) acc[mt][nt] = zz;

  for (int k0 = 0; k0 < 768; k0 += 32) {
    __syncthreads();
#pragma unroll
    for (int i = 0; i < 2; i++) {
      int cbase = w * 128 + i * 64;     // 16B-chunk base for this wave-instr
      int c = cbase + lane;             // chunk: row = c>>2, 8-elem quarter = c&3
      int r = c >> 2, q8 = c & 3;
      gload_lds16(xb + (size_t)(m0 + r) * 768 + k0 + q8 * 8, As + cbase * 8);
      gload_lds16(Wt + (size_t)(n0 + r) * 768 + k0 + q8 * 8, Bs + cbase * 8);
    }
    __syncthreads();
    bf16x8_t a[4], b[4];
#pragma unroll
    for (int mt = 0; mt < 4; mt++)
      a[mt] = *(const bf16x8_t*)(As + (mw + mt * 16 + (lane & 15)) * 32 + (lane >> 4) * 8);
#pragma unroll
    for (int nt = 0; nt < 4; nt++)
      b[nt] = *(const bf16x8_t*)(Bs + (nw + nt * 16 + (lane & 15)) * 32 + (lane >> 4) * 8);
#pragma unroll
    for (int mt = 0; mt < 4; mt++)
#pragma unroll
      for (int nt = 0; nt < 4; nt++)
        acc[mt][nt] = __builtin_amdgcn_mfma_f32_16x16x32_bf16(a[mt], b[nt], acc[mt][nt], 0, 0, 0);
  }

#pragma unroll
  for (int mt = 0; mt < 4; mt++) {
    int row0 = mw + mt * 16 + (lane >> 4) * 4;
#pragma unroll
    for (int nt = 0; nt < 4; nt++) {
      int col = nw + nt * 16 + (lane & 15);
      int n = n0 + col;
      int s = (n >> 6) & 15, h = n & 63, qk = n >> 10;
      float bv = bias[n];
#pragma unroll
      for (int j = 0; j < 4; j++) {
        int m = m0 + row0 + j;
        int bi = m >> 10, p = m & 1023;
        float v = acc[mt][nt][j] + bv;
        size_t off = ((size_t)(bi * 16 + s) * 1024 + p) * 64 + h;
        if (qk == 0) q_ws[off] = (bf16_t)(v * 0.125f);
        else         k_ws[off] = (bf16_t)v;
      }
    }
  }
}

// ---------------- rl[b][s][p] = 1 / sum_{k<=p} exp(score) ----------------
// grid (8 pblocks, 64 bs), 4 waves x 32 rows each via SWAPPED 32x32x16 MFMA
// (A=K rows=k, B=Q rows=p): C col = p (one p per lane), 16 regs = k-values.
// Row-sum is lane-local over regs/kt + one shfl_xor(32) for the hi half.
__global__ __launch_bounds__(256) void k_sumexp(const bf16_t* __restrict__ q_ws,
                                                const bf16_t* __restrict__ k_ws,
                                                float* __restrict__ rl_ws) {
  const int tid = threadIdx.x, lane = tid & 63, w = tid >> 6;
  const int bs = blockIdx.y;
  const int r0 = blockIdx.x * 128 + w * 32;
  const size_t base = (size_t)bs * 65536;  // 1024*64
  const int col = lane & 31, hi = lane >> 5;
  const int p = r0 + col;

  bf16x8_t qb[4];
  const bf16_t* qrow = q_ws + base + (size_t)p * 64 + hi * 8;
#pragma unroll
  for (int t = 0; t < 4; t++) qb[t] = *(const bf16x8_t*)(qrow + t * 16);

  float sum = 0.f;
  const int ktmax = r0 >> 5;
  for (int kt = 0; kt <= ktmax; kt++) {
    const bf16_t* krow = k_ws + base + (size_t)(kt * 32 + col) * 64 + hi * 8;
    bf16x8_t ka[4];
#pragma unroll
    for (int t = 0; t < 4; t++) ka[t] = *(const bf16x8_t*)(krow + t * 16);
    f32x16_t c;
#pragma unroll
    for (int j = 0; j < 16; j++) c[j] = 0.f;
#pragma unroll
    for (int t = 0; t < 4; t++)
      c = __builtin_amdgcn_mfma_f32_32x32x16_bf16(ka[t], qb[t], c, 0, 0, 0);
#pragma unroll
    for (int j = 0; j < 16; j++) {
      int kk = kt * 32 + (j & 3) + 8 * (j >> 2) + 4 * hi;
      if (kk <= p) sum += exp2f(c[j] * kLog2e);
    }
  }
  sum += __shfl_xor(sum, 32, 64);
  if (hi == 0) rl_ws[(size_t)bs * 1024 + p] = 1.0f / sum;
}

// ------- final: recompute scores, w=exp*rl, LN over 16 heads, write -------
// EXACT R8 body (proven optimum: 82.8us; six restructures R9-R12,R14 all
// regressed -- do not add structure around the accumulators). ONE knob this
// round: launch_bounds (512,4)->(512,6): VGPR cap ~84 (body needs ~75-80)
// -> 24 waves/CU instead of 16, +50% latency hiding. Failure signature if
// it spills: VGPR<=64 + FETCH explosion -> revert to (512,4).
__global__ __launch_bounds__(512, 6) void k_final(const bf16_t* __restrict__ q_ws,
                                                  const bf16_t* __restrict__ k_ws,
                                                  const float* __restrict__ rl_ws,
                                                  const float* __restrict__ ln_scale,
                                                  const float* __restrict__ ln_bias,
                                                  float* __restrict__ out) {
  const int tid = threadIdx.x, lane = tid & 63, w = tid >> 6;  // w in [0,8)
  const int raw = blockIdx.x;
  const int swz = (raw & 7) * 512 + (raw >> 3);  // XCD-contiguous chunks
  const int bb = swz >> 10, pb = (swz >> 5) & 31, kb = swz & 31;
  const int pbase = pb * 32, kbase = kb * 32;

  if (kbase > pbase + 31) {  // fully masked: w=0 for all heads -> out = ln_bias
#pragma unroll
    for (int it = 0; it < 8; it++) {
      int idx = it * 512 + tid;            // 0..4095 quads
      int s = idx >> 8, rem = idx & 255;   // 16 heads x (32p x 8 quads)
      int pl = rem >> 3, kq = (rem & 7) * 4;
      float bv = ln_bias[s];
      f32x4_t v = {bv, bv, bv, bv};
      __builtin_nontemporal_store(
          v, (f32x4_t*)(out + ((size_t)(bb * 16 + s) * 1024 + pbase + pl) * 1024 + kbase + kq));
    }
    return;
  }

  __shared__ float2 part[4][1024];  // [wavepair][cell = prl*32 + col] {sum,ssq}
                                    // after stage-2, part[0][cell] = {mu, rstd}
  __shared__ float  rl_lds[512];    // [s*32 + pr]

  const int col = lane & 31, hi = lane >> 5;
  const int kcol = kbase + col;
  const int s0 = w * 2, s1 = w * 2 + 1;

  // stage rl: one entry per thread (16 heads x 32 p-rows)
  rl_lds[tid] = rl_ws[(size_t)(bb * 16 + (tid >> 5)) * 1024 + pbase + (tid & 31)];

  // score tiles for this wave's 2 heads: A=Q (rows=p), B=K (rows=k)
  f32x16_t c0, c1;
#pragma unroll
  for (int j = 0; j < 16; j++) { c0[j] = 0.f; c1[j] = 0.f; }
  {
    size_t base0 = (size_t)(bb * 16 + s0) * 65536;
    const bf16_t* qrow = q_ws + base0 + (size_t)(pbase + col) * 64 + hi * 8;
    const bf16_t* krow = k_ws + base0 + (size_t)kcol * 64 + hi * 8;
#pragma unroll
    for (int t = 0; t < 4; t++)
      c0 = __builtin_amdgcn_mfma_f32_32x32x16_bf16(
          *(const bf16x8_t*)(qrow + t * 16), *(const bf16x8_t*)(krow + t * 16), c0, 0, 0, 0);
    qrow += 65536; krow += 65536;  // next head, same (b)
#pragma unroll
    for (int t = 0; t < 4; t++)
      c1 = __builtin_amdgcn_mfma_f32_32x32x16_bf16(
          *(const bf16x8_t*)(qrow + t * 16), *(const bf16x8_t*)(krow + t * 16), c1, 0, 0, 0);
  }

  __syncthreads();  // rl_lds ready

  // w = exp(score)*rl (causal), in place; no per-thread stat arrays
#pragma unroll
  for (int j = 0; j < 16; j++) {
    int prl = (j & 3) + 8 * (j >> 2) + 4 * hi;
    bool ok = (kcol <= pbase + prl);
    float w0 = ok ? exp2f(c0[j] * kLog2e) * rl_lds[s0 * 32 + prl] : 0.f;
    float w1 = ok ? exp2f(c1[j] * kLog2e) * rl_lds[s1 * 32 + prl] : 0.f;
    c0[j] = w0; c1[j] = w1;
  }

  // stage-1: waves 0-3 write their 2-head partials
  if (w < 4) {
#pragma unroll
    for (int j = 0; j < 16; j++) {
      int prl = (j & 3) + 8 * (j >> 2) + 4 * hi;
      part[w][prl * 32 + col] =
          make_float2(c0[j] + c1[j], c0[j] * c0[j] + c1[j] * c1[j]);
    }
  }
  __syncthreads();
  // waves 4-7 accumulate into partner slot (each wave covers each cell once)
  if (w >= 4) {
#pragma unroll
    for (int j = 0; j < 16; j++) {
      int prl = (j & 3) + 8 * (j >> 2) + 4 * hi;
      int cell = prl * 32 + col;
      float2 v = part[w - 4][cell];
      v.x += c0[j] + c1[j];
      v.y += c0[j] * c0[j] + c1[j] * c1[j];
      part[w - 4][cell] = v;
    }
  }
  __syncthreads();

  // stage-2: 512 threads x 2 cells; {mu,rstd} overwrites part[0]
#pragma unroll
  for (int r = 0; r < 2; r++) {
    int cell = tid + r * 512;
    float2 a = part[0][cell], b2 = part[1][cell];
    float2 cc = part[2][cell], d = part[3][cell];
    float sm = a.x + b2.x + cc.x + d.x;
    float sq = a.y + b2.y + cc.y + d.y;
    float m = sm * 0.0625f;
    part[0][cell] = make_float2(m, rsqrtf(sq * 0.0625f - m * m + 1e-5f));
  }
  __syncthreads();

  // stores: scalar dwords, nontemporal; lanes 0-31 cover one full 128B line
  // of row prl, lanes 32-63 the line of row prl+4.
  {
    float scl0 = ln_scale[s0], bi0 = ln_bias[s0];
    float scl1 = ln_scale[s1], bi1 = ln_bias[s1];
    size_t hb0 = ((size_t)(bb * 16 + s0) * 1024 + pbase) * 1024 + kbase;
    size_t hb1 = hb0 + (size_t)1048576;  // next head
#pragma unroll
    for (int j = 0; j < 16; j++) {
      int prl = (j & 3) + 8 * (j >> 2) + 4 * hi;
      float2 mr = part[0][prl * 32 + col];
      __builtin_nontemporal_store((c0[j] - mr.x) * mr.y * scl0 + bi0,
                                  &out[hb0 + (size_t)prl * 1024 + col]);
      __builtin_nontemporal_store((c1[j] - mr.x) * mr.y * scl1 + bi1,
                                  &out[hb1 + (size_t)prl * 1024 + col]);
    }
  }
}

extern "C" void kernel_launch(void* const* d_in, const int* in_sizes, int n_in,
                              void* d_out, int out_size, void* d_ws, size_t ws_size,
                              hipStream_t stream) {
  (void)in_sizes; (void)n_in; (void)out_size; (void)ws_size;
  const float* x        = (const float*)d_in[0];
  // d_in[1] = mask (causal tril; structure hardcoded)
  const float* W        = (const float*)d_in[2];
  const float* bias     = (const float*)d_in[3];
  const float* ln_scale = (const float*)d_in[4];
  const float* ln_bias  = (const float*)d_in[5];
  float* out = (float*)d_out;

  char* ws = (char*)d_ws;
  bf16_t* q_ws = (bf16_t*)ws;                    //  8,388,608 B [b][s][p][h]
  bf16_t* k_ws = (bf16_t*)(ws + 8388608);        //  8,388,608 B
  float*  rl_ws = (float*)(ws + 16777216);       //    262,144 B [b][s][p]
  bf16_t* xb   = (bf16_t*)(ws + 17039360);       //  6,291,456 B [4096][768]
  bf16_t* Wt   = (bf16_t*)(ws + 23330816);       //  3,145,728 B [2048][768]

  k_prep <<<dim3(3072), 256, 0, stream>>>(x, xb, W, Wt);
  k_proj <<<dim3(512), 256, 0, stream>>>(xb, Wt, bias, q_ws, k_ws);
  k_sumexp<<<dim3(8, 64), 256, 0, stream>>>(q_ws, k_ws, rl_ws);
  k_final<<<dim3(4096), 512, 0, stream>>>(q_ws, k_ws, rl_ws, ln_scale, ln_bias, out);
}

// Round 16
// 136.322 us; speedup vs baseline: 1.3339x; 1.2696x over previous
//
#include <hip/hip_runtime.h>
#include <hip/hip_bf16.h>
#include <math.h>

// WeightsOnlyAttention: qk proj (bf16 MFMA) -> causal softmax over k ->
// LayerNorm across S=16 heads -> out (4,16,1024,1024) fp32.
// B=4 P=1024 E=768 S=16 H=64.

typedef __bf16 bf16_t;
typedef __bf16 bf16x4_t __attribute__((ext_vector_type(4)));
typedef __bf16 bf16x8_t __attribute__((ext_vector_type(8)));
typedef float  f32x4_t  __attribute__((ext_vector_type(4)));
typedef float  f32x16_t __attribute__((ext_vector_type(16)));

#define DEV __device__ __forceinline__
static constexpr float kLog2e = 1.4426950408889634f;

DEV void gload_lds16(const bf16_t* g, bf16_t* l) {
  __builtin_amdgcn_global_load_lds(
      (const __attribute__((address_space(1))) void*)g,
      (__attribute__((address_space(3))) void*)l, 16, 0, 0);
}

// ---- fused prep: x->bf16 (blocks 0..1535) | W transpose (1536..3071) ----
__global__ __launch_bounds__(256) void k_prep(const float* __restrict__ x,
                                              bf16_t* __restrict__ xb,
                                              const float* __restrict__ W,
                                              bf16_t* __restrict__ Wt) {
  if (blockIdx.x < 1536) {
    size_t i = ((size_t)blockIdx.x * 256 + threadIdx.x) * 8;
    f32x4_t a = *(const f32x4_t*)(x + i);
    f32x4_t b = *(const f32x4_t*)(x + i + 4);
    bf16x8_t o = {(bf16_t)a[0], (bf16_t)a[1], (bf16_t)a[2], (bf16_t)a[3],
                  (bf16_t)b[0], (bf16_t)b[1], (bf16_t)b[2], (bf16_t)b[3]};
    *(bf16x8_t*)(xb + i) = o;
  } else {
    __shared__ float t[32][33];
    int b = blockIdx.x - 1536;           // 0..1535 = 64 n-blocks x 24 e-blocks
    int n0 = (b & 63) * 32, e0 = (b >> 6) * 32;
    int tx = threadIdx.x & 31, ty = threadIdx.x >> 5;  // 32x8
#pragma unroll
    for (int i = 0; i < 4; i++)
      t[ty + 8 * i][tx] = W[(size_t)(e0 + ty + 8 * i) * 2048 + n0 + tx];
    __syncthreads();
#pragma unroll
    for (int i = 0; i < 4; i++)
      Wt[(size_t)(n0 + ty + 8 * i) * 768 + e0 + tx] = (bf16_t)t[tx][ty + 8 * i];
  }
}

// ---------------- projection GEMM: C = xb * Wt^T + bias ----------------
// M=4096 (b,p), N=2048 (qk,s,h), K=768. 128x128 tile, BK=32, 4 waves.
// 1D grid 512, bijective XCD swizzle.
// Epilogue: q = (C+b)*0.125 -> q_ws[b][s][p][h] bf16 ; k -> k_ws.
__global__ __launch_bounds__(256) void k_proj(const bf16_t* __restrict__ xb,
                                              const bf16_t* __restrict__ Wt,
                                              const float* __restrict__ bias,
                                              bf16_t* __restrict__ q_ws,
                                              bf16_t* __restrict__ k_ws) {
  __shared__ bf16_t As[128 * 32];
  __shared__ bf16_t Bs[128 * 32];
  const int tid = threadIdx.x;
  const int lane = tid & 63;
  const int w = tid >> 6;
  const int raw = blockIdx.x;                  // 0..511
  const int swz = (raw & 7) * 64 + (raw >> 3); // XCD-contiguous chunks of 64
  const int m0 = (swz >> 4) * 128;             // 32 m-tiles
  const int n0 = (swz & 15) * 128;             // 16 n-tiles
  const int mw = (w >> 1) * 64, nw = (w & 1) * 64;

  f32x4_t zz = {0.f, 0.f, 0.f, 0.f};
  f32x4_t acc[4][4];
#pragma unroll
  for (int mt = 0; mt < 4; mt++)
#pragma unroll
    for (int nt = 0; nt < 4; nt++) acc[mt][nt] = zz;

  for (int k0 = 0; k0 < 768; k0 += 32) {
    __syncthreads();
#pragma unroll
    for (int i = 0; i < 2; i++) {
      int cbase = w * 128 + i * 64;     // 16B-chunk base for this wave-instr
      int c = cbase + lane;             // chunk: row = c>>2, 8-elem quarter = c&3
      int r = c >> 2, q8 = c & 3;
      gload_lds16(xb + (size_t)(m0 + r) * 768 + k0 + q8 * 8, As + cbase * 8);
      gload_lds16(Wt + (size_t)(n0 + r) * 768 + k0 + q8 * 8, Bs + cbase * 8);
    }
    __syncthreads();
    bf16x8_t a[4], b[4];
#pragma unroll
    for (int mt = 0; mt < 4; mt++)
      a[mt] = *(const bf16x8_t*)(As + (mw + mt * 16 + (lane & 15)) * 32 + (lane >> 4) * 8);
#pragma unroll
    for (int nt = 0; nt < 4; nt++)
      b[nt] = *(const bf16x8_t*)(Bs + (nw + nt * 16 + (lane & 15)) * 32 + (lane >> 4) * 8);
#pragma unroll
    for (int mt = 0; mt < 4; mt++)
#pragma unroll
      for (int nt = 0; nt < 4; nt++)
        acc[mt][nt] = __builtin_amdgcn_mfma_f32_16x16x32_bf16(a[mt], b[nt], acc[mt][nt], 0, 0, 0);
  }

#pragma unroll
  for (int mt = 0; mt < 4; mt++) {
    int row0 = mw + mt * 16 + (lane >> 4) * 4;
#pragma unroll
    for (int nt = 0; nt < 4; nt++) {
      int col = nw + nt * 16 + (lane & 15);
      int n = n0 + col;
      int s = (n >> 6) & 15, h = n & 63, qk = n >> 10;
      float bv = bias[n];
#pragma unroll
      for (int j = 0; j < 4; j++) {
        int m = m0 + row0 + j;
        int bi = m >> 10, p = m & 1023;
        float v = acc[mt][nt][j] + bv;
        size_t off = ((size_t)(bi * 16 + s) * 1024 + p) * 64 + h;
        if (qk == 0) q_ws[off] = (bf16_t)(v * 0.125f);
        else         k_ws[off] = (bf16_t)v;
      }
    }
  }
}

// ---------------- rl[b][s][p] = 1 / sum_{k<=p} exp(score) ----------------
// grid (8 pblocks, 64 bs), 4 waves x 32 rows each via SWAPPED 32x32x16 MFMA
// (A=K rows=k, B=Q rows=p): C col = p (one p per lane), 16 regs = k-values.
// Row-sum is lane-local over regs/kt + one shfl_xor(32) for the hi half.
__global__ __launch_bounds__(256) void k_sumexp(const bf16_t* __restrict__ q_ws,
                                                const bf16_t* __restrict__ k_ws,
                                                float* __restrict__ rl_ws) {
  const int tid = threadIdx.x, lane = tid & 63, w = tid >> 6;
  const int bs = blockIdx.y;
  const int r0 = blockIdx.x * 128 + w * 32;
  const size_t base = (size_t)bs * 65536;  // 1024*64
  const int col = lane & 31, hi = lane >> 5;
  const int p = r0 + col;

  bf16x8_t qb[4];
  const bf16_t* qrow = q_ws + base + (size_t)p * 64 + hi * 8;
#pragma unroll
  for (int t = 0; t < 4; t++) qb[t] = *(const bf16x8_t*)(qrow + t * 16);

  float sum = 0.f;
  const int ktmax = r0 >> 5;
  for (int kt = 0; kt <= ktmax; kt++) {
    const bf16_t* krow = k_ws + base + (size_t)(kt * 32 + col) * 64 + hi * 8;
    bf16x8_t ka[4];
#pragma unroll
    for (int t = 0; t < 4; t++) ka[t] = *(const bf16x8_t*)(krow + t * 16);
    f32x16_t c;
#pragma unroll
    for (int j = 0; j < 16; j++) c[j] = 0.f;
#pragma unroll
    for (int t = 0; t < 4; t++)
      c = __builtin_amdgcn_mfma_f32_32x32x16_bf16(ka[t], qb[t], c, 0, 0, 0);
#pragma unroll
    for (int j = 0; j < 16; j++) {
      int kk = kt * 32 + (j & 3) + 8 * (j >> 2) + 4 * hi;
      if (kk <= p) sum += exp2f(c[j] * kLog2e);
    }
  }
  sum += __shfl_xor(sum, 32, 64);
  if (hi == 0) rl_ws[(size_t)bs * 1024 + p] = 1.0f / sum;
}

// ------- final: recompute scores, w=exp*rl, LN over 16 heads, write -------
// EXACT R8 body at (512,4) -- the proven optimum (82.8us). Seven variants
// (R9 normal stores, R10/R11 LDS-transpose wide stores, R12 runtime tile
// loop, R14 dual-tile inline, R15 (512,6) occupancy knob) ALL regressed.
// Occupancy is quantized: 2 blocks/CU at <=128 VGPR, 3 at <=85; the body
// needs 86-128, so 2 blocks/CU is structural. Do not modify this kernel.
__global__ __launch_bounds__(512, 4) void k_final(const bf16_t* __restrict__ q_ws,
                                                  const bf16_t* __restrict__ k_ws,
                                                  const float* __restrict__ rl_ws,
                                                  const float* __restrict__ ln_scale,
                                                  const float* __restrict__ ln_bias,
                                                  float* __restrict__ out) {
  const int tid = threadIdx.x, lane = tid & 63, w = tid >> 6;  // w in [0,8)
  const int raw = blockIdx.x;
  const int swz = (raw & 7) * 512 + (raw >> 3);  // XCD-contiguous chunks
  const int bb = swz >> 10, pb = (swz >> 5) & 31, kb = swz & 31;
  const int pbase = pb * 32, kbase = kb * 32;

  if (kbase > pbase + 31) {  // fully masked: w=0 for all heads -> out = ln_bias
#pragma unroll
    for (int it = 0; it < 8; it++) {
      int idx = it * 512 + tid;            // 0..4095 quads
      int s = idx >> 8, rem = idx & 255;   // 16 heads x (32p x 8 quads)
      int pl = rem >> 3, kq = (rem & 7) * 4;
      float bv = ln_bias[s];
      f32x4_t v = {bv, bv, bv, bv};
      __builtin_nontemporal_store(
          v, (f32x4_t*)(out + ((size_t)(bb * 16 + s) * 1024 + pbase + pl) * 1024 + kbase + kq));
    }
    return;
  }

  __shared__ float2 part[4][1024];  // [wavepair][cell = prl*32 + col] {sum,ssq}
                                    // after stage-2, part[0][cell] = {mu, rstd}
  __shared__ float  rl_lds[512];    // [s*32 + pr]

  const int col = lane & 31, hi = lane >> 5;
  const int kcol = kbase + col;
  const int s0 = w * 2, s1 = w * 2 + 1;

  // stage rl: one entry per thread (16 heads x 32 p-rows)
  rl_lds[tid] = rl_ws[(size_t)(bb * 16 + (tid >> 5)) * 1024 + pbase + (tid & 31)];

  // score tiles for this wave's 2 heads: A=Q (rows=p), B=K (rows=k)
  f32x16_t c0, c1;
#pragma unroll
  for (int j = 0; j < 16; j++) { c0[j] = 0.f; c1[j] = 0.f; }
  {
    size_t base0 = (size_t)(bb * 16 + s0) * 65536;
    const bf16_t* qrow = q_ws + base0 + (size_t)(pbase + col) * 64 + hi * 8;
    const bf16_t* krow = k_ws + base0 + (size_t)kcol * 64 + hi * 8;
#pragma unroll
    for (int t = 0; t < 4; t++)
      c0 = __builtin_amdgcn_mfma_f32_32x32x16_bf16(
          *(const bf16x8_t*)(qrow + t * 16), *(const bf16x8_t*)(krow + t * 16), c0, 0, 0, 0);
    qrow += 65536; krow += 65536;  // next head, same (b)
#pragma unroll
    for (int t = 0; t < 4; t++)
      c1 = __builtin_amdgcn_mfma_f32_32x32x16_bf16(
          *(const bf16x8_t*)(qrow + t * 16), *(const bf16x8_t*)(krow + t * 16), c1, 0, 0, 0);
  }

  __syncthreads();  // rl_lds ready

  // w = exp(score)*rl (causal), in place; no per-thread stat arrays
#pragma unroll
  for (int j = 0; j < 16; j++) {
    int prl = (j & 3) + 8 * (j >> 2) + 4 * hi;
    bool ok = (kcol <= pbase + prl);
    float w0 = ok ? exp2f(c0[j] * kLog2e) * rl_lds[s0 * 32 + prl] : 0.f;
    float w1 = ok ? exp2f(c1[j] * kLog2e) * rl_lds[s1 * 32 + prl] : 0.f;
    c0[j] = w0; c1[j] = w1;
  }

  // stage-1: waves 0-3 write their 2-head partials
  if (w < 4) {
#pragma unroll
    for (int j = 0; j < 16; j++) {
      int prl = (j & 3) + 8 * (j >> 2) + 4 * hi;
      part[w][prl * 32 + col] =
          make_float2(c0[j] + c1[j], c0[j] * c0[j] + c1[j] * c1[j]);
    }
  }
  __syncthreads();
  // waves 4-7 accumulate into partner slot (each wave covers each cell once)
  if (w >= 4) {
#pragma unroll
    for (int j = 0; j < 16; j++) {
      int prl = (j & 3) + 8 * (j >> 2) + 4 * hi;
      int cell = prl * 32 + col;
      float2 v = part[w - 4][cell];
      v.x += c0[j] + c1[j];
      v.y += c0[j] * c0[j] + c1[j] * c1[j];
      part[w - 4][cell] = v;
    }
  }
  __syncthreads();

  // stage-2: 512 threads x 2 cells; {mu,rstd} overwrites part[0]
#pragma unroll
  for (int r = 0; r < 2; r++) {
    int cell = tid + r * 512;
    float2 a = part[0][cell], b2 = part[1][cell];
    float2 cc = part[2][cell], d = part[3][cell];
    float sm = a.x + b2.x + cc.x + d.x;
    float sq = a.y + b2.y + cc.y + d.y;
    float m = sm * 0.0625f;
    part[0][cell] = make_float2(m, rsqrtf(sq * 0.0625f - m * m + 1e-5f));
  }
  __syncthreads();

  // stores: scalar dwords, nontemporal; lanes 0-31 cover one full 128B line
  // of row prl, lanes 32-63 the line of row prl+4.
  {
    float scl0 = ln_scale[s0], bi0 = ln_bias[s0];
    float scl1 = ln_scale[s1], bi1 = ln_bias[s1];
    size_t hb0 = ((size_t)(bb * 16 + s0) * 1024 + pbase) * 1024 + kbase;
    size_t hb1 = hb0 + (size_t)1048576;  // next head
#pragma unroll
    for (int j = 0; j < 16; j++) {
      int prl = (j & 3) + 8 * (j >> 2) + 4 * hi;
      float2 mr = part[0][prl * 32 + col];
      __builtin_nontemporal_store((c0[j] - mr.x) * mr.y * scl0 + bi0,
                                  &out[hb0 + (size_t)prl * 1024 + col]);
      __builtin_nontemporal_store((c1[j] - mr.x) * mr.y * scl1 + bi1,
                                  &out[hb1 + (size_t)prl * 1024 + col]);
    }
  }
}

extern "C" void kernel_launch(void* const* d_in, const int* in_sizes, int n_in,
                              void* d_out, int out_size, void* d_ws, size_t ws_size,
                              hipStream_t stream) {
  (void)in_sizes; (void)n_in; (void)out_size; (void)ws_size;
  const float* x        = (const float*)d_in[0];
  // d_in[1] = mask (causal tril; structure hardcoded)
  const float* W        = (const float*)d_in[2];
  const float* bias     = (const float*)d_in[3];
  const float* ln_scale = (const float*)d_in[4];
  const float* ln_bias  = (const float*)d_in[5];
  float* out = (float*)d_out;

  char* ws = (char*)d_ws;
  bf16_t* q_ws = (bf16_t*)ws;                    //  8,388,608 B [b][s][p][h]
  bf16_t* k_ws = (bf16_t*)(ws + 8388608);        //  8,388,608 B
  float*  rl_ws = (float*)(ws + 16777216);       //    262,144 B [b][s][p]
  bf16_t* xb   = (bf16_t*)(ws + 17039360);       //  6,291,456 B [4096][768]
  bf16_t* Wt   = (bf16_t*)(ws + 23330816);       //  3,145,728 B [2048][768]

  k_prep <<<dim3(3072), 256, 0, stream>>>(x, xb, W, Wt);
  k_proj <<<dim3(512), 256, 0, stream>>>(xb, Wt, bias, q_ws, k_ws);
  k_sumexp<<<dim3(8, 64), 256, 0, stream>>>(q_ws, k_ws, rl_ws);
  k_final<<<dim3(4096), 512, 0, stream>>>(q_ws, k_ws, rl_ws, ln_scale, ln_bias, out);
}